// Round 4
// baseline (440.756 us; speedup 1.0000x reference)
//
#include <hip/hip_runtime.h>
#include <cstdint>

typedef unsigned short u16;
typedef unsigned int   u32;
typedef unsigned long long u64;

#define G_ROWS 20000
#define G_PAD  20096      // 157 * 128 (conv padding; gemm over-reads past this, guarded on store)
#define T_DIM  1536
#define D_DIM  512
#define B_DIM  256
#define TOPK   32
#define SIM_SCALE 0.04419417382415922f   // 1/sqrt(512), screening only
#define SQRT_D    22.62741699796952f     // f32(math.sqrt(512)) — np divides by this
#define BOUND_EPS 2.0e-4f                // per-element screen-vs-np error bound (true ~5e-6; 40x margin)

typedef __bf16 bf16x8 __attribute__((ext_vector_type(8)));
typedef float  f32x4  __attribute__((ext_vector_type(4)));

__device__ __forceinline__ u16 f2bf(float f) {
  u32 u = __float_as_uint(f);
  u += 0x7fffu + ((u >> 16) & 1u);   // RNE
  return (u16)(u >> 16);
}
__device__ __forceinline__ float bf2f(u16 h) {
  return __uint_as_float(((u32)h) << 16);
}
__device__ __forceinline__ u32 fkey(float v) {   // order-preserving f32 -> u32
  u32 b = __float_as_uint(v);
  return (b & 0x80000000u) ? ~b : (b | 0x80000000u);
}
__device__ __forceinline__ float funkey(u32 o) {
  u32 b = (o & 0x80000000u) ? (o & 0x7FFFFFFFu) : ~o;
  return __uint_as_float(b);
}

// ---------------- fused preprocessing: convA | convB | transpose ----------------
__global__ __launch_bounds__(256) void prep(const float* __restrict__ tg_dec,
                                            const float* __restrict__ tf_base,
                                            const float* __restrict__ tf_expr,
                                            u16* __restrict__ Ah, u16* __restrict__ Al,
                                            u16* __restrict__ Bh, u16* __restrict__ Bl,
                                            float* __restrict__ tfT)
{
  __shared__ float tile[32][33];
  const int b = blockIdx.x;
  const int tid = threadIdx.x;
  if (b < 10816) {
    const float* src; u16 *hi, *lo; int valid_rows; int bb;
    if (b < 10048) { src = tg_dec; hi = Ah; lo = Al; valid_rows = G_ROWS; bb = b; }
    else           { src = tf_base; hi = Bh; lo = Bl; valid_rows = T_DIM; bb = b - 10048; }
    size_t i = ((size_t)bb * 256 + tid) * 4;
    int row = (int)(i >> 9);
    float4 a = make_float4(0.f, 0.f, 0.f, 0.f);
    if (row < valid_rows) a = *(const float4*)(src + i);
    float v[4] = {a.x, a.y, a.z, a.w};
    u16 h[4], l[4];
#pragma unroll
    for (int c = 0; c < 4; ++c) {
      h[c] = f2bf(v[c]);
      l[c] = f2bf(v[c] - bf2f(h[c]));
    }
    *(uint2*)(hi + i) = make_uint2((u32)h[0] | ((u32)h[1] << 16), (u32)h[2] | ((u32)h[3] << 16));
    *(uint2*)(lo + i) = make_uint2((u32)l[0] | ((u32)l[1] << 16), (u32)l[2] | ((u32)l[3] << 16));
  } else {
    const int t = b - 10816;
    const int x = tid & 31, y = tid >> 5;
    const int bt = (t % 48) * 32;
    const int bb = (t / 48) * 32;
#pragma unroll
    for (int i = 0; i < 32; i += 8) tile[y + i][x] = tf_expr[(size_t)(bb + y + i) * T_DIM + bt + x];
    __syncthreads();
#pragma unroll
    for (int i = 0; i < 32; i += 8) tfT[(size_t)(bt + y + i) * B_DIM + bb + x] = tile[x][y + i];
  }
}

// ---------------- async global -> LDS, 16B/lane ----------------
__device__ __forceinline__ void gl16(const u16* g, u16* l) {
  __builtin_amdgcn_global_load_lds((__attribute__((address_space(1))) void*)(void*)g,
                                   (__attribute__((address_space(3))) void*)l, 16, 0, 0);
}

// ---------------- screening GEMM: C ~= (Ah+Al)(Bh+Bl)^T via 3 bf16 MFMA terms ----------------
// 256x256 tile, BK=32, 8 waves, 4 half-buffers, 128 KiB LDS.
// 2 barriers per K-tile (hazard-minimal): (a) post-vmcnt tile handshake; (b) before STAGE_A
// overwrites the live A-buffer. Plain ds_reads inside the region — compiler emits fine-grained
// lgkmcnt(N) and interleaves reads with MFMA (no manual lgkmcnt(0) drains).
// Counted vmcnt: vmcnt(4) in steady state, vmcnt(0) only at kt=15.
// Epilogue fuses motif-mask: Sim = mask ? acc*scale : -inf (moves mask read out of topk).
#define NBX 6             // 1536 / 256
#define NWG 474           // 79 * 6

__global__ __launch_bounds__(512, 2) void gemm_split(const u16* __restrict__ Ah, const u16* __restrict__ Al,
                                                     const u16* __restrict__ Bh, const u16* __restrict__ Bl,
                                                     const int* __restrict__ Mask,
                                                     float* __restrict__ Sim)
{
  // u16 map: A-buf p at p*16384 (Ah 8192 | Al 8192); B-buf p at 32768 + p*16384 (Bh | Bl)
  __shared__ u16 sm[65536];   // 128 KiB

  // bijective XCD swizzle (m204; NWG % 8 == 2)
  const int orig = blockIdx.x;
  const int xcd  = orig & 7;
  const int q    = NWG >> 3, r = NWG & 7;
  const int wgid = (xcd < r ? xcd * (q + 1) : r * (q + 1) + (xcd - r) * q) + (orig >> 3);
  const int by   = wgid / NBX;
  const int bx   = wgid - by * NBX;
  const int bm0  = by * 256;
  const int bn0  = bx * 256;

  const int tid  = threadIdx.x;
  const int lane = tid & 63;
  const int wv   = tid >> 6;      // 0..7
  const int wm   = wv >> 2;       // 0..1 : wave row  (128-row strip)
  const int wn   = wv & 3;        // 0..3 : wave col  (64-col strip)
  const int la8  = lane << 3;     // u16 offset of this lane's 16B chunk in a subtile

  // staging roles: wave wv stages subtiles {2wv, 2wv+1}; subtile = 16 rows x 32 k,
  // 64 chunks of 16B in lane order (LDS dest linear: chunk l = lane l).
  const int sub  = wv << 1;
  const int srow = lane & 15;
  const int skc  = (lane >> 4) << 3;
  const u16* gA0  = Ah + (size_t)(bm0 + (sub + 0) * 16 + srow) * 512 + skc;
  const u16* gA1  = Ah + (size_t)(bm0 + (sub + 1) * 16 + srow) * 512 + skc;
  const u16* gAl0 = Al + (size_t)(bm0 + (sub + 0) * 16 + srow) * 512 + skc;
  const u16* gAl1 = Al + (size_t)(bm0 + (sub + 1) * 16 + srow) * 512 + skc;
  const u16* gB0  = Bh + (size_t)(bn0 + (sub + 0) * 16 + srow) * 512 + skc;
  const u16* gB1  = Bh + (size_t)(bn0 + (sub + 1) * 16 + srow) * 512 + skc;
  const u16* gBl0 = Bl + (size_t)(bn0 + (sub + 0) * 16 + srow) * 512 + skc;
  const u16* gBl1 = Bl + (size_t)(bn0 + (sub + 1) * 16 + srow) * 512 + skc;

#define STAGE_A(p, ktn) do {                                   \
    const size_t ko = (size_t)(ktn) << 5;                      \
    u16* d = sm + (p) * 16384 + sub * 512;                     \
    gl16(gA0 + ko,  d);                                        \
    gl16(gA1 + ko,  d + 512);                                  \
    gl16(gAl0 + ko, d + 8192);                                 \
    gl16(gAl1 + ko, d + 8192 + 512);                           \
  } while (0)
#define STAGE_B(p, ktn) do {                                   \
    const size_t ko = (size_t)(ktn) << 5;                      \
    u16* d = sm + 32768 + (p) * 16384 + sub * 512;             \
    gl16(gB0 + ko,  d);                                        \
    gl16(gB1 + ko,  d + 512);                                  \
    gl16(gBl0 + ko, d + 8192);                                 \
    gl16(gBl1 + ko, d + 8192 + 512);                           \
  } while (0)

  f32x4 acc[8][4];
#pragma unroll
  for (int i = 0; i < 8; ++i)
#pragma unroll
    for (int j = 0; j < 4; ++j) acc[i][j] = (f32x4){0.f, 0.f, 0.f, 0.f};

  bf16x8 aH[4], aL[4], bH[4], bL[4];

#define READ_A(rbA, half) do {                                                     \
    _Pragma("unroll")                                                              \
    for (int i = 0; i < 4; ++i) {                                                  \
      aH[i] = *(const bf16x8*)((rbA) + (wm * 8 + (half) * 4 + i) * 512 + la8);     \
      aL[i] = *(const bf16x8*)((rbA) + 8192 + (wm * 8 + (half) * 4 + i) * 512 + la8); \
    }                                                                              \
  } while (0)
#define READ_B(rbB, half) do {                                                     \
    _Pragma("unroll")                                                              \
    for (int i = 0; i < 2; ++i) {                                                  \
      bH[(half) * 2 + i] = *(const bf16x8*)((rbB) + (wn * 4 + (half) * 2 + i) * 512 + la8); \
      bL[(half) * 2 + i] = *(const bf16x8*)((rbB) + 8192 + (wn * 4 + (half) * 2 + i) * 512 + la8); \
    }                                                                              \
  } while (0)
#define MFMA_Q(qm, qn) do {                                                        \
    _Pragma("unroll")                                                              \
    for (int m2 = 0; m2 < 4; ++m2)                                                 \
      _Pragma("unroll")                                                            \
      for (int n2 = 0; n2 < 2; ++n2) {                                             \
        const int mi = (qm) * 4 + m2, ni = (qn) * 2 + n2;                          \
        acc[mi][ni] = __builtin_amdgcn_mfma_f32_16x16x32_bf16(aH[m2], bH[ni], acc[mi][ni], 0, 0, 0); \
        acc[mi][ni] = __builtin_amdgcn_mfma_f32_16x16x32_bf16(aH[m2], bL[ni], acc[mi][ni], 0, 0, 0); \
        acc[mi][ni] = __builtin_amdgcn_mfma_f32_16x16x32_bf16(aL[m2], bH[ni], acc[mi][ni], 0, 0, 0); \
      }                                                                            \
  } while (0)
#define SBAR do { __builtin_amdgcn_sched_barrier(0); __builtin_amdgcn_s_barrier(); __builtin_amdgcn_sched_barrier(0); } while (0)

  // prologue: A(0), B(0), A(1) in flight (12 loads/wave)
  STAGE_A(0, 0);
  STAGE_B(0, 0);
  STAGE_A(1, 1);

#pragma unroll 2
  for (int kt = 0; kt < 16; ++kt) {
    const u16* rbA = sm + (kt & 1) * 16384;
    const u16* rbB = sm + 32768 + (kt & 1) * 16384;

    // tile handshake: A(kt),B(kt) landed; A(kt+1) stays in flight (kt<15)
    if (kt < 15) asm volatile("s_waitcnt vmcnt(4)" ::: "memory");
    else         asm volatile("s_waitcnt vmcnt(0)" ::: "memory");
    SBAR;

    // region 1 (compiler-scheduled: ds_reads interleave with MFMA via auto lgkmcnt(N))
    READ_A(rbA, 0);
    READ_B(rbB, 0);
    if (kt < 15) STAGE_B((kt + 1) & 1, kt + 1);   // other B-buffer: no hazard with rbB reads
    MFMA_Q(0, 0);
    READ_B(rbB, 1);
    MFMA_Q(0, 1);
    READ_A(rbA, 1);                                // same buffer re-read: no barrier needed
    MFMA_Q(1, 0);                                  // consumes all A/B reads of this tile

    SBAR;                                          // all waves' A-buf reads retired
    if (kt < 14) STAGE_A(kt & 1, kt + 2);          // overwrite A-buf[kt&1] for tile kt+2
    __builtin_amdgcn_s_setprio(1);
    MFMA_Q(1, 1);                                  // pure-register quadrant
    __builtin_amdgcn_s_setprio(0);
  }
#undef STAGE_A
#undef STAGE_B
#undef READ_A
#undef READ_B
#undef MFMA_Q
#undef SBAR

  // epilogue: fused motif-mask -> Sim (masked = -inf), screening scale on the rest
  const float NEG_INF = __uint_as_float(0xff800000u);
  const int erow0 = bm0 + (wm << 7) + ((lane >> 4) << 2);
  const int ecol0 = bn0 + (wn << 6) + (lane & 15);
#pragma unroll
  for (int mi = 0; mi < 8; ++mi)
#pragma unroll
    for (int rr = 0; rr < 4; ++rr) {
      int row = erow0 + mi * 16 + rr;
      if (row < G_ROWS) {
        const int* mrow = Mask + (size_t)row * T_DIM + ecol0;
        float*     srow = Sim  + (size_t)row * T_DIM + ecol0;
#pragma unroll
        for (int ni = 0; ni < 4; ++ni) {
          int m = mrow[ni * 16];
          srow[ni * 16] = m ? acc[mi][ni][rr] * SIM_SCALE : NEG_INF;
        }
      }
    }
}

// ---------------- helpers ----------------
__device__ __forceinline__ int count_ge(const float* v, float tau) {
  int c = 0;
#pragma unroll
  for (int j = 0; j < 24; ++j) c += (int)__popcll(__ballot(v[j] >= tau));
  return c;
}
// full 64-lane bitonic sort, descending by u64 key; returns this lane's sorted key
__device__ __forceinline__ u64 bitonic64_desc(u64 key, int lane) {
#pragma unroll
  for (int k = 2; k <= 64; k <<= 1) {
#pragma unroll
    for (int j = k >> 1; j > 0; j >>= 1) {
      u64 p = __shfl_xor(key, j, 64);
      bool lower = (lane & j) == 0;
      bool asc   = (lane & k) != 0;
      u64 mn = (key < p) ? key : p;
      u64 mx = (key < p) ? p : key;
      key = (lower == asc) ? mn : mx;
    }
  }
  return key;
}

// ---------------- per-row (1 wave/row): Sim arrives pre-masked (-inf) from gemm ----------------
__global__ __launch_bounds__(256) void topk_kernel(float* __restrict__ Sim,
                                                   const float* __restrict__ tg_dec,
                                                   const float* __restrict__ tf_base,
                                                   int* __restrict__ tIdx, float* __restrict__ tW)
{
  __shared__ u32 cval[4][64];
  __shared__ int cidxs[4][64];
  const int lane = threadIdx.x & 63;
  const int wv   = threadIdx.x >> 6;
  const int g    = blockIdx.x * 4 + wv;
  float* row = Sim + (size_t)g * T_DIM;

  // --- vectorized load of pre-masked sim ---
  float v[24];
#pragma unroll
  for (int j = 0; j < 6; ++j) {
    float4 q = *(const float4*)(row + j * 256 + lane * 4);
    v[j * 4 + 0] = q.x; v[j * 4 + 1] = q.y; v[j * 4 + 2] = q.z; v[j * 4 + 3] = q.w;
  }

  // --- parallel 6-threshold ladder count (pure VALU) + valid count ---
  const float TH0 = 1.25f, TH1 = 1.40f, TH2 = 1.55f, TH3 = 1.70f, TH4 = 1.85f, TH5 = 2.00f;
  int n0 = 0, n1 = 0, n2 = 0, n3 = 0, n4 = 0, n5 = 0, nv = 0;
#pragma unroll
  for (int j = 0; j < 24; ++j) {
    float x = v[j];
    n0 += (x >= TH0); n1 += (x >= TH1); n2 += (x >= TH2);
    n3 += (x >= TH3); n4 += (x >= TH4); n5 += (x >= TH5);
    nv += (x != -INFINITY);
  }
  u64 p0 = (u64)(u32)n0 | ((u64)(u32)n1 << 16) | ((u64)(u32)n2 << 32) | ((u64)(u32)n3 << 48);
  u64 p1 = (u64)(u32)n4 | ((u64)(u32)n5 << 16) | ((u64)(u32)nv << 32);
#pragma unroll
  for (int off = 32; off > 0; off >>= 1) {
    p0 += __shfl_xor(p0, off, 64);
    p1 += __shfl_xor(p1, off, 64);
  }
  int c[6];
  c[0] = (int)(p0 & 0xFFFF); c[1] = (int)((p0 >> 16) & 0xFFFF);
  c[2] = (int)((p0 >> 32) & 0xFFFF); c[3] = (int)((p0 >> 48) & 0xFFFF);
  c[4] = (int)(p1 & 0xFFFF); c[5] = (int)((p1 >> 16) & 0xFFFF);
  const int cvalid = (int)((p1 >> 32) & 0xFFFF);

  // --- pick largest threshold with count >= 33; fallback bisect for gaps/extremes (~1%) ---
  float tau; int cnt;
  if (cvalid <= 64) { tau = -3.0e38f; cnt = cvalid; }
  else {
    int is = -1;
#pragma unroll
    for (int i = 0; i < 6; ++i) if (c[i] >= 33) is = i;
    const float THv[7] = {TH0, TH1, TH2, TH3, TH4, TH5, 8.0f};
    if (is >= 0 && c[is] <= 64) { tau = THv[is]; cnt = c[is]; }
    else {
      float lo, hi;
      if (is < 0) { lo = -4.0f; hi = TH0; }
      else        { lo = THv[is]; hi = THv[is + 1]; }
      tau = lo; cnt = 1000;
      for (int it = 0; it < 16; ++it) {
        float mid = 0.5f * (lo + hi);
        int cm = count_ge(v, mid);
        if (cm > 64)      lo = mid;
        else if (cm < 33) hi = mid;
        else { tau = mid; cnt = cm; break; }
      }
      if (cnt == 1000) tau = lo;
    }
  }

  // --- ballot-prefix compaction into wave-private LDS ---
  int base = 0;
#pragma unroll
  for (int j = 0; j < 24; ++j) {
    bool pred = (v[j] >= tau);
    u64 bmc = __ballot(pred);
    int pos = base + (int)__popcll(bmc & ((1ull << lane) - 1ull));
    int idx = (j >> 2) * 256 + lane * 4 + (j & 3);
    if (pred && pos < 64) { cval[wv][pos] = fkey(v[j]); cidxs[wv][pos] = idx; }
    base += (int)__popcll(bmc);
  }
  const int cnt_eff = (base < 64) ? base : 64;

  u64 key = 0;
  if (lane < cnt_eff)
    key = ((u64)cval[wv][lane] << 32) | (u64)(u32)(~(u32)cidxs[wv][lane]);

  key = bitonic64_desc(key, lane);
  int   myidx = (int)(~(u32)key);
  float myv   = (key != 0) ? funkey((u32)(key >> 32)) : -INFINITY;

  // --- np-replica ONLY if the 31/32 cut is truly contested ---
  float v31 = __shfl(myv, 31, 64);
  float v32 = __shfl(myv, 32, 64);
  if (cnt_eff > TOPK && (v31 - v32) < 2.0f * BOUND_EPS) {
    bool flag = (lane < cnt_eff) &&
                (myv >= v32 - 2.0f * BOUND_EPS) && (myv <= v31 + 2.0f * BOUND_EPS);
    if (flag) {
      // bit-exact np replica: OpenBLAS sgemm sequential-K FMA chain, kc split 384|128
      const float* arow_g = tg_dec + (size_t)g * D_DIM;
      const float* brow   = tf_base + (size_t)myidx * D_DIM;
      float s1 = 0.f, s2 = 0.f;
#pragma unroll 8
      for (int k = 0; k < 384; k += 4) {
        float4 av = *(const float4*)(arow_g + k);
        float4 bv = *(const float4*)(brow + k);
        s1 = fmaf(av.x, bv.x, s1); s1 = fmaf(av.y, bv.y, s1);
        s1 = fmaf(av.z, bv.z, s1); s1 = fmaf(av.w, bv.w, s1);
      }
#pragma unroll 8
      for (int k = 384; k < 512; k += 4) {
        float4 av = *(const float4*)(arow_g + k);
        float4 bv = *(const float4*)(brow + k);
        s2 = fmaf(av.x, bv.x, s2); s2 = fmaf(av.y, bv.y, s2);
        s2 = fmaf(av.z, bv.z, s2); s2 = fmaf(av.w, bv.w, s2);
      }
      myv = (s1 + s2) / SQRT_D;
      key = ((u64)fkey(myv) << 32) | (u64)(u32)(~(u32)myidx);
    }
    key = bitonic64_desc(key, lane);
    myidx = (int)(~(u32)key);
    myv   = (key != 0) ? funkey((u32)(key >> 32)) : -INFINITY;
  }

  // --- weights from sorted lanes 0..31 ---
  const bool selme = (lane < TOPK) && (lane < cnt_eff);
  float mx = __shfl(myv, 0, 64);
  float e = selme ? __expf(myv - mx) : 0.f;
  float E = e;
#pragma unroll
  for (int off = 32; off > 0; off >>= 1) E += __shfl_xor(E, off, 64);
  float rden = (E > 0.f) ? (1.f / E) : 0.f;
  float w = e * rden;

  // --- dense zero write from registers, drain, then sparse scatter ---
  const float4 z4 = make_float4(0.f, 0.f, 0.f, 0.f);
#pragma unroll
  for (int j = 0; j < 6; ++j) *(float4*)(row + j * 256 + lane * 4) = z4;
  asm volatile("s_waitcnt vmcnt(0)" ::: "memory");
  if (selme) row[myidx] = w;

  if (cnt_eff < TOPK && lane >= cnt_eff && lane < TOPK) {
    tIdx[(size_t)g * TOPK + lane] = 0; tW[(size_t)g * TOPK + lane] = 0.f;
  }
  if (selme) {
    tIdx[(size_t)g * TOPK + lane] = myidx;
    tW[(size_t)g * TOPK + lane]   = w;
  }
}

// ---------------- out0[b,g] = scale * sum_k w[g,k] * tfT[idx[g,k], b] ----------------
// per-wave: 4 g-rows; per-thread: 4 b-values via float4 gathers (wave load = full 1KB row)
__global__ __launch_bounds__(256) void combine_kernel(const float* __restrict__ tfT, const int* __restrict__ tIdx,
                                                      const float* __restrict__ tW, const float* __restrict__ scalep,
                                                      float* __restrict__ out0)
{
  __shared__ int   sIdx[16 * 32];
  __shared__ float sW[16 * 32];
  const int tid  = threadIdx.x;
  const int lane = tid & 63;
  const int wv   = tid >> 6;
  const int g0   = blockIdx.x * 16;
  for (int i = tid; i < 512; i += 256) {
    sIdx[i] = tIdx[(size_t)g0 * 32 + i];
    sW[i]   = tW[(size_t)g0 * 32 + i];
  }
  __syncthreads();
  const float scale = scalep[0];
  const int gl = wv << 2;                      // this wave's 4 local g-rows
  float acc[4][4];
#pragma unroll
  for (int gi = 0; gi < 4; ++gi)
#pragma unroll
    for (int c = 0; c < 4; ++c) acc[gi][c] = 0.f;

#pragma unroll 4
  for (int k = 0; k < 32; ++k) {
#pragma unroll
    for (int gi = 0; gi < 4; ++gi) {
      int   t = sIdx[(gl + gi) * 32 + k];
      float w = sW[(gl + gi) * 32 + k];
      float4 vv = *(const float4*)(tfT + (size_t)t * B_DIM + lane * 4);
      acc[gi][0] = fmaf(w, vv.x, acc[gi][0]);
      acc[gi][1] = fmaf(w, vv.y, acc[gi][1]);
      acc[gi][2] = fmaf(w, vv.z, acc[gi][2]);
      acc[gi][3] = fmaf(w, vv.w, acc[gi][3]);
    }
  }
  // write: for each of this thread's 4 b-values, float4 across its wave's 4 consecutive g
#pragma unroll
  for (int c = 0; c < 4; ++c) {
    float4 o = make_float4(scale * acc[0][c], scale * acc[1][c], scale * acc[2][c], scale * acc[3][c]);
    *(float4*)(out0 + (size_t)(lane * 4 + c) * G_ROWS + g0 + gl) = o;
  }
}

extern "C" void kernel_launch(void* const* d_in, const int* in_sizes, int n_in,
                              void* d_out, int out_size, void* d_ws, size_t ws_size,
                              hipStream_t stream)
{
  const float* tg_dec     = (const float*)d_in[0];
  const float* tf_base    = (const float*)d_in[1];
  const float* tf_expr    = (const float*)d_in[2];
  const int*   motif_mask = (const int*)d_in[3];
  const float* scale      = (const float*)d_in[4];

  float* out0 = (float*)d_out;                           // [B, G]
  float* attn = out0 + (size_t)B_DIM * G_ROWS;           // [G, T] — Sim scratch, overwritten in place

  char* ws = (char*)d_ws;
  u16*   Ah    = (u16*)(ws);                             // G_PAD*512 bf16
  u16*   Al    = (u16*)(ws + 20578304);
  u16*   Bh    = (u16*)(ws + 41156608);                  // 1536*512 bf16
  u16*   Bl    = (u16*)(ws + 42729472);
  float* tfT   = (float*)(ws + 44302336);                // [T, B] f32
  int*   tIdx  = (int*)(ws + 45875200);                  // [G, 32]
  float* tW    = (float*)(ws + 48435200);                // [G, 32]

  prep<<<11200, 256, 0, stream>>>(tg_dec, tf_base, tf_expr, Ah, Al, Bh, Bl, tfT);
  gemm_split<<<NWG, 512, 0, stream>>>(Ah, Al, Bh, Bl, motif_mask, attn);
  topk_kernel<<<5000, 256, 0, stream>>>(attn, tg_dec, tf_base, tIdx, tW);
  combine_kernel<<<1250, 256, 0, stream>>>(tfT, tIdx, tW, scale, out0);
}